// Round 6
// baseline (944.368 us; speedup 1.0000x reference)
//
#include <hip/hip_runtime.h>
#include <hip/hip_bf16.h>

typedef unsigned int  uint32;
typedef unsigned short ushort16;

#define B_TOTAL 65536
#define NN 17

typedef __bf16 bf16x8 __attribute__((ext_vector_type(8)));
typedef float  f32x4  __attribute__((ext_vector_type(4)));

// ---- fixed normalized adjacency (from EDGES in the reference) ----
static constexpr int   CNT[NN]    = {2,0,0,0,0,4,4,2,2,1,1,3,3,2,2,1,1};
static constexpr int   NBR[NN][4] = {
  {5,6,0,0},{0,0,0,0},{0,0,0,0},{0,0,0,0},{0,0,0,0},
  {7,6,11,0},{8,5,12,0},{5,9,0,0},{6,10,0,0},{7,0,0,0},{8,0,0,0},
  {5,12,13,0},{6,11,14,0},{11,15,0,0},{12,16,0,0},{13,0,0,0},{14,0,0,0}};
static constexpr float INVDEG[NN] = {0.5f,0.f,0.f,0.f,0.f,0.25f,0.25f,0.5f,0.5f,1.f,1.f,
  0.33333333333333333f,0.33333333333333333f,0.5f,0.5f,1.f,1.f};

// ---- workspace layout (bytes) ----
#define S_BYTES   ((size_t)B_TOTAL * 1088 * 2)
#define STATS_OFF S_BYTES
#define W1_OFF    (STATS_OFF + 1024)
#define W2_OFF    (W1_OFF + (size_t)1088*256*2)
#define WG1_OFF   (W2_OFF + (size_t)256*128*2)   // WgH1[4096], WgL1[4096]
#define WG2_OFF   (WG1_OFF + 16384)              // WgH2[4096], WgL2[4096]

__device__ inline float bf2f_lo(uint32 v){ return __uint_as_float(v << 16); }
__device__ inline float bf2f_hi(uint32 v){ return __uint_as_float(v & 0xffff0000u); }
__device__ inline ushort16 f2bfu(float f){
  union { __hip_bfloat16 h; ushort16 u; } c; c.h = __float2bfloat16(f); return c.u;
}
__device__ inline float bfval(ushort16 u){ return __uint_as_float(((uint32)u) << 16); }
__device__ inline float bfround(float f){ return bfval(f2bfu(f)); }
__device__ inline void split2(float f, ushort16& h, ushort16& l){
  h = f2bfu(f);
  l = f2bfu(f - bfval(h));
}

__device__ inline f32x4 MFMA(bf16x8 a, bf16x8 b, f32x4 c){
  return __builtin_amdgcn_mfma_f32_16x16x32_bf16(a, b, c, 0, 0, 0);
}

// encoder + normalized-adjacency aggregate (round-3-validated helper)
__device__ inline void enc_agg(const float* __restrict__ xb,
                               float we0, float we1, float be, float* s1){
  float h[NN];
  #pragma unroll
  for (int n = 0; n < NN; ++n)
    h[n] = fmaxf(fmaf(xb[2*n], we0, fmaf(xb[2*n+1], we1, be)), 0.f);
  #pragma unroll
  for (int n = 0; n < NN; ++n){
    float a = 0.f;
    #pragma unroll
    for (int j = 0; j < 4; ++j) if (j < CNT[n]) a += h[NBR[n][j]];
    s1[n] = fmaf(INVDEG[n], a, h[n]);
  }
}

__device__ inline void reduce_stats(float* sA, float* qA,
                                    float* __restrict__ gSum, float* __restrict__ gSq){
  int t = threadIdx.x;
  #pragma unroll
  for (int n = 0; n < NN; ++n){
    float s = sA[n], q = qA[n];
    #pragma unroll
    for (int off = 32; off > 0; off >>= 1){
      s += __shfl_down(s, off, 64);
      q += __shfl_down(q, off, 64);
    }
    sA[n] = s; qA[n] = q;
  }
  __shared__ float shS[NN], shQ[NN];
  if (t < NN){ shS[t] = 0.f; shQ[t] = 0.f; }
  __syncthreads();
  if ((t & 63) == 0){
    #pragma unroll
    for (int n = 0; n < NN; ++n){ atomicAdd(&shS[n], sA[n]); atomicAdd(&shQ[n], qA[n]); }
  }
  __syncthreads();
  if (t < NN){ atomicAdd(&gSum[t], shS[t]); atomicAdd(&gSq[t], shQ[t]); }
}

// ---- pre-cast + transpose weights; gc weights as bf16 hi/lo split ----
__global__ __launch_bounds__(256) void k_prep(const float* __restrict__ Wp1,
                                              const float* __restrict__ Wp2,
                                              const float* __restrict__ Wg1,
                                              const float* __restrict__ Wg2,
                                              ushort16* __restrict__ W1T,
                                              ushort16* __restrict__ W2T,
                                              ushort16* __restrict__ WgH1,
                                              ushort16* __restrict__ WgL1,
                                              ushort16* __restrict__ WgH2,
                                              ushort16* __restrict__ WgL2){
  int g = blockIdx.x * 256 + threadIdx.x;          // 1248*256 = 319,488
  if (g < 278528){
    int n = g / 1088, k = g - n*1088;              // W1T[n][k] = W_p1[k][n]
    W1T[g] = f2bfu(Wp1[(size_t)k*256 + n]);
  } else if (g < 311296){
    int h = g - 278528;
    int e = h >> 8, k = h & 255;                   // W2T[e][k] = W_p2[k][e]
    W2T[h] = f2bfu(Wp2[(size_t)k*128 + e]);
  } else if (g < 315392){
    int h = g - 311296;
    int e = h >> 6, d = h & 63;                    // WgT[e][d] = W_gc[d][e], split
    ushort16 hi, lo; split2(Wg1[d*64 + e], hi, lo);
    WgH1[h] = hi; WgL1[h] = lo;
  } else if (g < 319488){
    int h = g - 315392;
    int e = h >> 6, d = h & 63;
    ushort16 hi, lo; split2(Wg2[d*64 + e], hi, lo);
    WgH2[h] = hi; WgL2[h] = lo;
  }
}

// ---- pass 1: BN1 statistics (round-3-validated version) ----
__global__ __launch_bounds__(256,2) void k_stats1(const float* __restrict__ x,
    const float* __restrict__ W_enc, const float* __restrict__ b_enc,
    float* __restrict__ gSum, float* __restrict__ gSq){
  int t = threadIdx.x, e = t & 63, lb = t >> 6;
  float we0 = W_enc[e], we1 = W_enc[64 + e], be = b_enc[e];
  float sA[NN], qA[NN];
  #pragma unroll
  for (int n = 0; n < NN; ++n){ sA[n] = 0.f; qA[n] = 0.f; }
  size_t b0 = (size_t)blockIdx.x * 32;
  for (int it = 0; it < 8; ++it){
    size_t b = b0 + it*4 + lb;
    float s1[NN];
    enc_agg(x + b*34, we0, we1, be, s1);
    #pragma unroll
    for (int n = 0; n < NN; ++n){ sA[n] += s1[n]; qA[n] += s1[n]*s1[n]; }
  }
  reduce_stats(sA, qA, gSum, gSq);
}

__global__ void k_finalize(const float* __restrict__ gSum, const float* __restrict__ gSq,
                           const float* __restrict__ gamma, const float* __restrict__ beta,
                           float* __restrict__ scale, float* __restrict__ shift){
  int n = threadIdx.x;
  if (n < NN){
    const float invC = 1.0f / (float)((size_t)B_TOTAL * 64);
    float mean = gSum[n] * invC;
    float var  = gSq[n]  * invC - mean*mean;
    float istd = rsqrtf(var + 1e-5f);
    float sc   = gamma[n] * istd;
    scale[n] = sc;
    shift[n] = fmaf(-mean, sc, beta[n]);
  }
}

// ---- graph-conv: round-5 skeleton, SCALAR fp32 core (bisection round).
// Same LDS layout (hi/lo split rows, 272 B stride, 2 node-phases), same lane
// mapping for outputs (b = lane&15, e = w*16 + q*4 + r). If this passes, the
// bug is in the MFMA fragment core; if it fails, in the skeleton.
template<int MODE>
__global__ __launch_bounds__(256) void k_gcx(
    const float* __restrict__ x,
    const float* __restrict__ W_enc, const float* __restrict__ b_enc,
    const ushort16* __restrict__ WgH, const ushort16* __restrict__ WgL,
    const float* __restrict__ bg,
    const float* __restrict__ scale, const float* __restrict__ shift,
    __hip_bfloat16* __restrict__ Sg,
    float* __restrict__ gSum, float* __restrict__ gSq){
  __shared__ __align__(16) char lds[41344];
  __shared__ float sc_s[NN], sf_s[NN];
  const int t = threadIdx.x;
  const int L = t & 63, w = t >> 6, lo = L & 15, q = L >> 4;
  const size_t b0 = (size_t)blockIdx.x * 16;
  char* s1T = lds;
  char* Sb  = (char*)Sg;
  if (t < NN){ sc_s[t] = scale[t]; sf_s[t] = shift[t]; }

  float s1v[NN][4];                                // MODE 0: BN1'd s1 (fp32)
  if constexpr (MODE == 0){
    float* xbuf = (float*)(lds + 39168);
    if (t < 136) ((uint4*)xbuf)[t] = ((const uint4*)(x + b0*34))[t];
    __syncthreads();
    const int b = t >> 4, eg = t & 15;
    const float* xb = xbuf + b*34;
    float4 we0 = *(const float4*)&W_enc[eg*4];
    float4 we1 = *(const float4*)&W_enc[64 + eg*4];
    float4 bev = *(const float4*)&b_enc[eg*4];
    float h[NN][4];
    #pragma unroll
    for (int n = 0; n < NN; ++n){
      float x0 = xb[2*n], x1 = xb[2*n+1];
      h[n][0] = fmaxf(fmaf(x0, we0.x, fmaf(x1, we1.x, bev.x)), 0.f);
      h[n][1] = fmaxf(fmaf(x0, we0.y, fmaf(x1, we1.y, bev.y)), 0.f);
      h[n][2] = fmaxf(fmaf(x0, we0.z, fmaf(x1, we1.z, bev.z)), 0.f);
      h[n][3] = fmaxf(fmaf(x0, we0.w, fmaf(x1, we1.w, bev.w)), 0.f);
    }
    #pragma unroll
    for (int n = 0; n < NN; ++n){
      float a0=0.f,a1=0.f,a2=0.f,a3=0.f;
      #pragma unroll
      for (int j = 0; j < 4; ++j) if (j < CNT[n]){
        a0 += h[NBR[n][j]][0]; a1 += h[NBR[n][j]][1];
        a2 += h[NBR[n][j]][2]; a3 += h[NBR[n][j]][3];
      }
      float sc = sc_s[n], sf = sf_s[n];
      s1v[n][0] = fmaf(fmaf(INVDEG[n], a0, h[n][0]), sc, sf);
      s1v[n][1] = fmaf(fmaf(INVDEG[n], a1, h[n][1]), sc, sf);
      s1v[n][2] = fmaf(fmaf(INVDEG[n], a2, h[n][2]), sc, sf);
      s1v[n][3] = fmaf(fmaf(INVDEG[n], a3, h[n][3]), sc, sf);
    }
  } else {
    __syncthreads();                               // sc_s visibility
  }

  const char* WgHb = (const char*)WgH;
  const char* WgLb = (const char*)WgL;
  const int e0off = w*16 + q*4;                    // this lane's 4 output e rows

  float accf[NN][4];
  #pragma unroll
  for (int n = 0; n < NN; ++n){
    #pragma unroll
    for (int r = 0; r < 4; ++r) accf[n][r] = 0.f;
  }

  #pragma unroll
  for (int p = 0; p < 2; ++p){
    const int n0 = p ? 9 : 0;
    const int n1 = p ? 17 : 9;
    __syncthreads();                               // prior-phase LDS reads done
    if constexpr (MODE == 0){
      const int b = t >> 4, eg = t & 15;
      for (int n = n0; n < n1; ++n){
        ushort16 h0,h1,h2,h3,l0,l1,l2,l3;
        split2(s1v[n][0], h0, l0); split2(s1v[n][1], h1, l1);
        split2(s1v[n][2], h2, l2); split2(s1v[n][3], h3, l3);
        char* rowp = s1T + (size_t)((n - n0)*16 + b)*272;
        uint2 uh, ul;
        uh.x = (uint32)h0 | ((uint32)h1 << 16); uh.y = (uint32)h2 | ((uint32)h3 << 16);
        ul.x = (uint32)l0 | ((uint32)l1 << 16); ul.y = (uint32)l2 | ((uint32)l3 << 16);
        *(uint2*)(rowp + eg*8)       = uh;
        *(uint2*)(rowp + 128 + eg*8) = ul;
      }
    } else {
      if (p == 0){
        #pragma unroll
        for (int i = 0; i < 5; ++i){
          int c = t + i*256;
          if (c < 1152){                           // 16 b x 9 nodes x 8 chunks
            int b = c / 72, r = c - b*72;
            int n = r >> 3, rr = r & 7;
            uint4 v = *(const uint4*)(Sb + (b0 + b)*2176 + (size_t)(n*8 + rr)*16);
            float sc = sc_s[n], sf = sf_s[n];
            uint4 vh, vl;
            ushort16 hh, ll;
            uint32 pw[4] = {v.x, v.y, v.z, v.w};
            uint32 oh[4], ol[4];
            #pragma unroll
            for (int k2 = 0; k2 < 4; ++k2){
              float fa = fmaf(bf2f_lo(pw[k2]), sc, sf);
              float fb = fmaf(bf2f_hi(pw[k2]), sc, sf);
              split2(fa, hh, ll); oh[k2] = hh; ol[k2] = ll;
              split2(fb, hh, ll); oh[k2] |= ((uint32)hh << 16); ol[k2] |= ((uint32)ll << 16);
            }
            vh.x=oh[0]; vh.y=oh[1]; vh.z=oh[2]; vh.w=oh[3];
            vl.x=ol[0]; vl.y=ol[1]; vl.z=ol[2]; vl.w=ol[3];
            char* rowp = s1T + (size_t)(n*16 + b)*272;
            *(uint4*)(rowp + rr*16)       = vh;
            *(uint4*)(rowp + 128 + rr*16) = vl;
          }
        }
      } else {
        #pragma unroll
        for (int i = 0; i < 4; ++i){
          int c = t + i*256;                       // 16 b x 8 nodes x 8 chunks = 1024
          int b = c >> 6, r = c & 63;
          int n = 9 + (r >> 3), rr = r & 7;
          uint4 v = *(const uint4*)(Sb + (b0 + b)*2176 + (size_t)(n*8 + rr)*16);
          float sc = sc_s[n], sf = sf_s[n];
          uint4 vh, vl;
          ushort16 hh, ll;
          uint32 pw[4] = {v.x, v.y, v.z, v.w};
          uint32 oh[4], ol[4];
          #pragma unroll
          for (int k2 = 0; k2 < 4; ++k2){
            float fa = fmaf(bf2f_lo(pw[k2]), sc, sf);
            float fb = fmaf(bf2f_hi(pw[k2]), sc, sf);
            split2(fa, hh, ll); oh[k2] = hh; ol[k2] = ll;
            split2(fb, hh, ll); oh[k2] |= ((uint32)hh << 16); ol[k2] |= ((uint32)ll << 16);
          }
          vh.x=oh[0]; vh.y=oh[1]; vh.z=oh[2]; vh.w=oh[3];
          vl.x=ol[0]; vl.y=ol[1]; vl.z=ol[2]; vl.w=ol[3];
          char* rowp = s1T + (size_t)((n - 9)*16 + b)*272;
          *(uint4*)(rowp + rr*16)       = vh;
          *(uint4*)(rowp + 128 + rr*16) = vl;
        }
      }
    }
    __syncthreads();

    // ---- SCALAR core: accf[n][r] += sum_d s1[b=lo][n][d] * W[d][e0off+r] ----
    #pragma unroll 1
    for (int dd = 0; dd < 8; ++dd){
      float Wv[4][8];
      #pragma unroll
      for (int r = 0; r < 4; ++r){
        uint4 wh = *(const uint4*)(WgHb + (size_t)(e0off + r)*128 + dd*16);
        uint4 wl = *(const uint4*)(WgLb + (size_t)(e0off + r)*128 + dd*16);
        uint32 hw[4] = {wh.x, wh.y, wh.z, wh.w};
        uint32 lw[4] = {wl.x, wl.y, wl.z, wl.w};
        #pragma unroll
        for (int k2 = 0; k2 < 4; ++k2){
          Wv[r][2*k2]   = bf2f_lo(hw[k2]) + bf2f_lo(lw[k2]);
          Wv[r][2*k2+1] = bf2f_hi(hw[k2]) + bf2f_hi(lw[k2]);
        }
      }
      #pragma unroll
      for (int nn = 0; nn < 9; ++nn){
        int n = n0 + nn;
        if (n >= n1) break;
        const char* base = s1T + (size_t)((n - n0)*16 + lo)*272;
        uint4 sh = *(const uint4*)(base + dd*16);
        uint4 sl = *(const uint4*)(base + 128 + dd*16);
        uint32 hs[4] = {sh.x, sh.y, sh.z, sh.w};
        uint32 ls[4] = {sl.x, sl.y, sl.z, sl.w};
        float sv[8];
        #pragma unroll
        for (int k2 = 0; k2 < 4; ++k2){
          sv[2*k2]   = bf2f_lo(hs[k2]) + bf2f_lo(ls[k2]);
          sv[2*k2+1] = bf2f_hi(hs[k2]) + bf2f_hi(ls[k2]);
        }
        #pragma unroll
        for (int r = 0; r < 4; ++r){
          float a = accf[n][r];
          #pragma unroll
          for (int j = 0; j < 8; ++j) a = fmaf(sv[j], Wv[r][j], a);
          accf[n][r] = a;
        }
      }
    }
  }

  // bias + relu; lane owns (b=lo, e = e0off + r)
  float4 bgv = *(const float4*)&bg[e0off];
  const float bga[4] = {bgv.x, bgv.y, bgv.z, bgv.w};
  #pragma unroll
  for (int n = 0; n < NN; ++n){
    #pragma unroll
    for (int r = 0; r < 4; ++r)
      accf[n][r] = fmaxf(accf[n][r] + bga[r], 0.f);
  }

  uint2 uo[NN];
  float sA[NN], qA[NN];
  if constexpr (MODE == 0){
    #pragma unroll
    for (int n = 0; n < NN; ++n){
      float sr[4];
      #pragma unroll
      for (int r = 0; r < 4; ++r){
        float ag = 0.f;
        #pragma unroll
        for (int j = 0; j < 4; ++j) if (j < CNT[n]) ag += accf[NBR[n][j]][r];
        sr[r] = fmaf(INVDEG[n], ag, accf[n][r]);
      }
      uo[n].x = (uint32)f2bfu(sr[0]) | ((uint32)f2bfu(sr[1]) << 16);
      uo[n].y = (uint32)f2bfu(sr[2]) | ((uint32)f2bfu(sr[3]) << 16);
      float r0 = bfround(sr[0]), r1 = bfround(sr[1]);
      float r2 = bfround(sr[2]), r3 = bfround(sr[3]);
      sA[n] = r0+r1+r2+r3;
      qA[n] = r0*r0 + r1*r1 + r2*r2 + r3*r3;
    }
  } else {
    #pragma unroll
    for (int n = 0; n < NN; ++n){
      uo[n].x = (uint32)f2bfu(accf[n][0]) | ((uint32)f2bfu(accf[n][1]) << 16);
      uo[n].y = (uint32)f2bfu(accf[n][2]) | ((uint32)f2bfu(accf[n][3]) << 16);
    }
  }
  __syncthreads();                                 // all s1T reads done
  char* sOut = lds;                                // alias: 16 rows x 2192B
  #pragma unroll
  for (int n = 0; n < NN; ++n)
    *(uint2*)(sOut + lo*2192 + n*128 + e0off*2) = uo[n];
  __syncthreads();
  #pragma unroll
  for (int i = 0; i < 9; ++i){
    int c = t + i*256;
    if (c < 2176){
      int b = c / 136, r = c - b*136;
      *(uint4*)(Sb + (b0 + b)*2176 + (size_t)r*16) =
          *(const uint4*)(sOut + b*2192 + r*16);
    }
  }
  if constexpr (MODE == 0) reduce_stats(sA, qA, gSum, gSq);
}

// ---- MFMA pooled MLP + L2 normalize (unchanged, validated) ----
__global__ __launch_bounds__(256,2) void k_mlp(const ushort16* __restrict__ S,
    const ushort16* __restrict__ W1T, const float* __restrict__ b_p1,
    const ushort16* __restrict__ W2T, const float* __restrict__ b_p2,
    float* __restrict__ out){
  __shared__ __align__(16) char smem[65536];
  const int t = threadIdx.x;
  const int L = t & 63, w = t >> 6;
  const int lo = L & 15, q = L >> 4;
  const size_t b0 = (size_t)blockIdx.x * 128;
  const char* Sb  = (const char*)S;
  const char* W1b = (const char*)W1T;
  const char* W2b = (const char*)W2T;

  f32x4 acc[16][2];
  #pragma unroll
  for (int nt = 0; nt < 16; ++nt){ acc[nt][0] = (f32x4)0.f; acc[nt][1] = (f32x4)0.f; }

  uint4 pr0, pr1, wr0, wr1, wr2, wr3;
  const int rowP = t >> 2,            partP = t & 3;
  const int rowP2 = (256 + t) >> 2,   partP2 = t & 3;
  auto loadG = [&](int ks){
    size_t kb = (size_t)ks * 64;
    pr0 = *(const uint4*)(Sb + (b0 + rowP )*2176 + kb + partP *16);
    pr1 = *(const uint4*)(Sb + (b0 + rowP2)*2176 + kb + partP2*16);
    wr0 = *(const uint4*)(W1b + (size_t)((  0 + t) >> 2)*2176 + kb + partP*16);
    wr1 = *(const uint4*)(W1b + (size_t)((256 + t) >> 2)*2176 + kb + partP*16);
    wr2 = *(const uint4*)(W1b + (size_t)((512 + t) >> 2)*2176 + kb + partP*16);
    wr3 = *(const uint4*)(W1b + (size_t)((768 + t) >> 2)*2176 + kb + partP*16);
  };
  auto writeL = [&](int buf){
    char* Pb = smem + (buf ? 8192 : 0);
    char* Wb = smem + 16384 + (buf ? 16384 : 0);
    *(uint4*)(Pb + (size_t)t*16)          = pr0;
    *(uint4*)(Pb + (size_t)(256 + t)*16)  = pr1;
    *(uint4*)(Wb + (size_t)t*16)          = wr0;
    *(uint4*)(Wb + (size_t)(256 + t)*16)  = wr1;
    *(uint4*)(Wb + (size_t)(512 + t)*16)  = wr2;
    *(uint4*)(Wb + (size_t)(768 + t)*16)  = wr3;
  };

  loadG(0); writeL(0);
  __syncthreads();
  #pragma unroll 1
  for (int ks = 0; ks < 34; ++ks){
    const int cur = ks & 1;
    const char* Pb = smem + (cur ? 8192 : 0);
    const char* Wb = smem + 16384 + (cur ? 16384 : 0);
    if (ks < 33) loadG(ks + 1);
    bf16x8 pf0 = *(const bf16x8*)(Pb + (w*32 +  0 + lo)*64 + q*16);
    bf16x8 pf1 = *(const bf16x8*)(Pb + (w*32 + 16 + lo)*64 + q*16);
    #pragma unroll
    for (int nt = 0; nt < 16; ++nt){
      bf16x8 wf = *(const bf16x8*)(Wb + (nt*16 + lo)*64 + q*16);
      acc[nt][0] = MFMA(wf, pf0, acc[nt][0]);
      acc[nt][1] = MFMA(wf, pf1, acc[nt][1]);
    }
    if (ks < 33) writeL(cur ^ 1);
    __syncthreads();
  }

  #pragma unroll
  for (int nt = 0; nt < 16; ++nt){
    float4 bias = *(const float4*)&b_p1[nt*16 + q*4];
    #pragma unroll
    for (int bt = 0; bt < 2; ++bt){
      int b = w*32 + bt*16 + lo;
      f32x4 v = acc[nt][bt];
      float z0 = fmaxf(v.x + bias.x, 0.f), z1 = fmaxf(v.y + bias.y, 0.f);
      float z2 = fmaxf(v.z + bias.z, 0.f), z3 = fmaxf(v.w + bias.w, 0.f);
      uint32 lo32 = (uint32)f2bfu(z0) | ((uint32)f2bfu(z1) << 16);
      uint32 hi32 = (uint32)f2bfu(z2) | ((uint32)f2bfu(z3) << 16);
      int nbyte = (nt*16 + q*4) * 2;
      int addr = b*512 + (nbyte ^ ((b & 7) << 4));
      *(uint2*)(smem + addr) = make_uint2(lo32, hi32);
    }
  }
  __syncthreads();

  f32x4 acc2[8][2];
  #pragma unroll
  for (int et = 0; et < 8; ++et){ acc2[et][0] = (f32x4)0.f; acc2[et][1] = (f32x4)0.f; }
  #pragma unroll 1
  for (int ks = 0; ks < 8; ++ks){
    bf16x8 zf0, zf1;
    {
      int b = w*32 + lo;
      int kb = ks*64 + q*16;
      zf0 = *(const bf16x8*)(smem + b*512 + (kb ^ ((b & 7) << 4)));
      b = w*32 + 16 + lo;
      zf1 = *(const bf16x8*)(smem + b*512 + (kb ^ ((b & 7) << 4)));
    }
    #pragma unroll
    for (int et = 0; et < 8; ++et){
      bf16x8 wf = *(const bf16x8*)(W2b + (et*16 + lo)*512 + ks*64 + q*16);
      acc2[et][0] = MFMA(wf, zf0, acc2[et][0]);
      acc2[et][1] = MFMA(wf, zf1, acc2[et][1]);
    }
  }

  #pragma unroll
  for (int bt = 0; bt < 2; ++bt){
    int b = w*32 + bt*16 + lo;
    float4 vv[8];
    float ss = 0.f;
    #pragma unroll
    for (int et = 0; et < 8; ++et){
      float4 bias = *(const float4*)&b_p2[et*16 + q*4];
      f32x4 a = bt ? acc2[et][1] : acc2[et][0];
      vv[et].x = a.x + bias.x; vv[et].y = a.y + bias.y;
      vv[et].z = a.z + bias.z; vv[et].w = a.w + bias.w;
      ss += vv[et].x*vv[et].x + vv[et].y*vv[et].y + vv[et].z*vv[et].z + vv[et].w*vv[et].w;
    }
    ss += __shfl_xor(ss, 16, 64);
    ss += __shfl_xor(ss, 32, 64);
    float inv = 1.0f / fmaxf(sqrtf(ss), 1e-12f);
    float* op = out + (b0 + b)*128;
    #pragma unroll
    for (int et = 0; et < 8; ++et){
      float4 o; o.x = vv[et].x*inv; o.y = vv[et].y*inv; o.z = vv[et].z*inv; o.w = vv[et].w*inv;
      *(float4*)(op + et*16 + q*4) = o;
    }
  }
}

extern "C" void kernel_launch(void* const* d_in, const int* in_sizes, int n_in,
                              void* d_out, int out_size, void* d_ws, size_t ws_size,
                              hipStream_t stream) {
  const float* x     = (const float*)d_in[0];
  const float* W_enc = (const float*)d_in[1];
  const float* b_enc = (const float*)d_in[2];
  const float* W_gc1 = (const float*)d_in[3];
  const float* b_gc1 = (const float*)d_in[4];
  const float* W_gc2 = (const float*)d_in[5];
  const float* b_gc2 = (const float*)d_in[6];
  const float* gamma1= (const float*)d_in[7];
  const float* beta1 = (const float*)d_in[8];
  const float* gamma2= (const float*)d_in[9];
  const float* beta2 = (const float*)d_in[10];
  const float* W_p1  = (const float*)d_in[11];
  const float* b_p1  = (const float*)d_in[12];
  const float* W_p2  = (const float*)d_in[13];
  const float* b_p2  = (const float*)d_in[14];
  float* out = (float*)d_out;

  char* ws = (char*)d_ws;
  __hip_bfloat16* S = (__hip_bfloat16*)ws;
  float*    stats = (float*)(ws + STATS_OFF);
  ushort16* W1T   = (ushort16*)(ws + W1_OFF);
  ushort16* W2T   = (ushort16*)(ws + W2_OFF);
  ushort16* WgH1  = (ushort16*)(ws + WG1_OFF);
  ushort16* WgL1  = (ushort16*)(ws + WG1_OFF + 8192);
  ushort16* WgH2  = (ushort16*)(ws + WG2_OFF);
  ushort16* WgL2  = (ushort16*)(ws + WG2_OFF + 8192);

  (void)hipMemsetAsync(stats, 0, 512, stream);

  k_prep<<<1248, 256, 0, stream>>>(W_p1, W_p2, W_gc1, W_gc2,
                                   W1T, W2T, WgH1, WgL1, WgH2, WgL2);
  k_stats1<<<2048, 256, 0, stream>>>(x, W_enc, b_enc, stats + 0, stats + 32);
  k_finalize<<<1, 32, 0, stream>>>(stats + 0, stats + 32, gamma1, beta1, stats + 128, stats + 160);
  k_gcx<0><<<4096, 256, 0, stream>>>(x, W_enc, b_enc, WgH1, WgL1, b_gc1,
                                     stats + 128, stats + 160, S, stats + 64, stats + 96);
  k_finalize<<<1, 32, 0, stream>>>(stats + 64, stats + 96, gamma2, beta2, stats + 192, stats + 224);
  k_gcx<1><<<4096, 256, 0, stream>>>(nullptr, nullptr, nullptr, WgH2, WgL2, b_gc2,
                                     stats + 192, stats + 224, S, nullptr, nullptr);
  k_mlp<<<512, 256, 0, stream>>>((const ushort16*)S, W1T, b_p1, (const ushort16*)W2T, b_p2, out);
}